// Round 8
// baseline (392.652 us; speedup 1.0000x reference)
//
#include <hip/hip_runtime.h>
#include <hip/hip_bf16.h>
#include <math.h>

// Fully-fused TCN, R7 (resubmit — previous bench was an infra failure):
// R6 structure (chunk=64 outputs, window=128, swapped MFMA operands, packed
// b64 epilogues, 2 LDS regions = 69.6 KB), with the latency fix:
// __launch_bounds__(512) (no reg cap) + conv_core preloads ALL weight
// fragments into registers before the MFMA loop (one vmcnt batch per conv
// instead of per-kc exposed global latency).

typedef __attribute__((ext_vector_type(8))) short short8;
typedef __attribute__((ext_vector_type(4))) short short4v;
typedef __attribute__((ext_vector_type(4))) float floatx4;

#define S_LEN 4096
#define STRIDE 136               // 128 ch + 8 pad (bf16 elems)
#define REG_ELEMS (128 * STRIDE) // 17408 shorts per region
#define LDS_BYTES (2 * REG_ELEMS * 2)  // 69632 B

// weight bank offsets (bf16-bit shorts)
#define OFF_L0C1_0 0
#define OFF_L0C1_1 8192
#define OFF_L0C2_0 16384
#define OFF_L0C2_1 32768
#define OFF_DS     49152
#define OFF_C1B    57344      // + lvl*32768 ; tap1 at +16384
#define OFF_C2B    188416     // + lvl*32768 ; tap1 at +16384

__device__ __forceinline__ float elu_f(float v) {
    return v > 0.0f ? v : (__expf(v) - 1.0f);
}
__device__ __forceinline__ short f2bs(float v) {
    __hip_bfloat16 h = __float2bfloat16(v);
    return *reinterpret_cast<short*>(&h);
}
__device__ __forceinline__ float bs2f(short s) {
    __hip_bfloat16 h = *reinterpret_cast<__hip_bfloat16*>(&s);
    return __bfloat162float(h);
}
__device__ __forceinline__ short4v pack4(const floatx4 v) {
    __hip_bfloat162 p0 = __float22bfloat162_rn(make_float2(v[0], v[1]));
    __hip_bfloat162 p1 = __float22bfloat162_rn(make_float2(v[2], v[3]));
    short4v r;
    r[0] = ((const short*)&p0)[0]; r[1] = ((const short*)&p0)[1];
    r[2] = ((const short*)&p1)[0]; r[3] = ((const short*)&p1)[1];
    return r;
}

// ---------------------------------------------------------------------------
// Swapped-operand conv: D[m=co][n=s] = sum_ci W[co][ci] * X[s(-d)][ci].
// Per wave: 4 m-tiles (64 co) x 2 n-tiles (32 rows).
// ALL weight fragments preloaded to registers first (batched global latency),
// then the LDS-read + MFMA loop runs without exposed global stalls.
// ---------------------------------------------------------------------------
template<int KCH, int TAPS>
__device__ __forceinline__ void conv_core(
    const short* __restrict__ Lin, const int d,
    const short* __restrict__ w0, const short* __restrict__ w1,
    const int srow, const int l16, const int quad, const int cobase,
    floatx4 (&acc)[4][2])
{
    constexpr int CIN = KCH * 32;

    // ---- batch-load all weight fragments for this conv
    short8 wf0[KCH][4], wf1[KCH][4];
    #pragma unroll
    for (int kc = 0; kc < KCH; ++kc) {
        #pragma unroll
        for (int mt = 0; mt < 4; ++mt) {
            const int co = cobase + mt * 16 + l16;
            wf1[kc][mt] = *(const short8*)(w1 + co * CIN + kc * 32 + quad * 8);
            if (TAPS == 2)
                wf0[kc][mt] = *(const short8*)(w0 + co * CIN + kc * 32 + quad * 8);
        }
    }

    #pragma unroll
    for (int mt = 0; mt < 4; ++mt)
        #pragma unroll
        for (int nt = 0; nt < 2; ++nt) acc[mt][nt] = {0.f, 0.f, 0.f, 0.f};

    #pragma unroll
    for (int kc = 0; kc < KCH; ++kc) {
        #pragma unroll
        for (int nt = 0; nt < 2; ++nt) {
            const int r   = srow + nt * 16 + l16;
            const int col = kc * 32 + quad * 8;
            const short8 b1 = *(const short8*)(Lin + r * STRIDE + col);
            short8 b0 = b1;
            if (TAPS == 2) {
                int r0 = r - d; if (r0 < 0) r0 = 0;   // clamped rows never consumed
                b0 = *(const short8*)(Lin + r0 * STRIDE + col);
            }
            #pragma unroll
            for (int mt = 0; mt < 4; ++mt) {
                if (TAPS == 2)
                    acc[mt][nt] = __builtin_amdgcn_mfma_f32_16x16x32_bf16(wf0[kc][mt], b0, acc[mt][nt], 0, 0, 0);
                acc[mt][nt] = __builtin_amdgcn_mfma_f32_16x16x32_bf16(wf1[kc][mt], b1, acc[mt][nt], 0, 0, 0);
            }
        }
    }
}

// ---------------------------------------------------------------------------
// Packed epilogue. Lane holds co = cobase+mt*16+quad*4+rr at s = srow+nt*16+l16.
// MODE 0: elu(acc+b) ; MODE 1: acc+b ; MODE 2: elu(elu(acc+b)+dst) (in-place res)
// ---------------------------------------------------------------------------
template<int MODE, bool KEEP>
__device__ __forceinline__ void store_tile(short* __restrict__ dst,
    const floatx4 (&acc)[4][2], const float* __restrict__ bias,
    int cobase, int srow, int l16, int quad, int zero_below, short4v* keep)
{
    #pragma unroll
    for (int mt = 0; mt < 4; ++mt) {
        const int co4 = cobase + mt * 16 + quad * 4;
        const floatx4 bb = *(const floatx4*)(bias + co4);
        #pragma unroll
        for (int nt = 0; nt < 2; ++nt) {
            const int sl = srow + nt * 16 + l16;
            short* p = dst + sl * STRIDE + co4;
            floatx4 y;
            #pragma unroll
            for (int rr = 0; rr < 4; ++rr) {
                float v = acc[mt][nt][rr] + bb[rr];
                if (MODE != 1) v = elu_f(v);
                y[rr] = v;
            }
            if (MODE == 2) {
                const short4v old = *(const short4v*)p;
                #pragma unroll
                for (int rr = 0; rr < 4; ++rr) y[rr] = elu_f(y[rr] + bs2f(old[rr]));
            }
            if (sl < zero_below) y = {0.f, 0.f, 0.f, 0.f};
            const short4v pk = pack4(y);
            *(short4v*)p = pk;
            if (KEEP) keep[mt * 2 + nt] = pk;
        }
    }
}

// ---------------------------------------------------------------------------
__global__ __launch_bounds__(512)
void tcn_fused(const float* __restrict__ x,     // fp32 [16,64,4096] channel-first
               const short* __restrict__ wq,
               const float* __restrict__ b1_0, const float* __restrict__ b2_0,
               const float* __restrict__ ds_b, const float* __restrict__ B1,
               const float* __restrict__ B2, float* __restrict__ out)
{
    extern __shared__ short L[];
    short* RA = L;                 // T buffer (also X staging, cols 0..63)
    short* RB = L + REG_ELEMS;     // D buffer (residual chain)

    const int tid  = threadIdx.x;
    const int wave = tid >> 6, lane = tid & 63;
    const int l16  = lane & 15, quad = lane >> 4;
    const int coh  = wave & 1,  sq   = wave >> 1;
    const int cobase = coh * 64;
    const int srow   = sq * 32;
    const int s0  = blockIdx.x * 64;
    const int s0g = s0 - 64;
    const int b   = blockIdx.y;
    const int zb  = (s0 == 0) ? 64 : 0;   // zero rows with global s < 0

    // ---- stage X: fp32 channel-first -> bf16 [row][ci] in RA (cols 0..63)
    {
        const float* xp = x + (size_t)b * 64 * S_LEN;
        #pragma unroll
        for (int c8 = 0; c8 < 8; ++c8) {
            const int c = wave * 8 + c8;
            #pragma unroll
            for (int h = 0; h < 2; ++h) {
                const int r = lane + h * 64;
                const int s = s0g + r;
                const float v = (s >= 0) ? xp[c * S_LEN + s] : 0.f;
                RA[r * STRIDE + c] = f2bs(v);
            }
        }
    }
    __syncthreads();

    floatx4 acc[4][2];
    short4v x1keep[8];

    // ---- ds (1x1): reads X (RA cols 0..63), writes RB.
    conv_core<2, 1>(RA, 0, nullptr, wq + OFF_DS, srow, l16, quad, cobase, acc);
    store_tile<1, false>(RB, acc, ds_b, cobase, srow, l16, quad, zb, nullptr);

    // ---- conv1_0 (d=1): reads X (RA), stores T over RA after barrier.
    conv_core<2, 2>(RA, 1, wq + OFF_L0C1_0, wq + OFF_L0C1_1, srow, l16, quad, cobase, acc);
    __syncthreads();                                   // all X reads done
    store_tile<0, false>(RA, acc, b1_0, cobase, srow, l16, quad, zb, nullptr);
    __syncthreads();

    // ---- c2_0 (d=1): reads T(RA), res = ds in RB -> RB in-place; keep x1 regs
    conv_core<4, 2>(RA, 1, wq + OFF_L0C2_0, wq + OFF_L0C2_1, srow, l16, quad, cobase, acc);
    store_tile<2, true>(RB, acc, b2_0, cobase, srow, l16, quad, zb, x1keep);
    __syncthreads();

    // ---- levels 1..3 (d = 2, 4, 8)
    #pragma unroll
    for (int lvl = 0; lvl < 3; ++lvl) {
        const int d = 2 << lvl;
        const short* wc1 = wq + OFF_C1B + lvl * 32768;
        const short* wc2 = wq + OFF_C2B + lvl * 32768;
        conv_core<4, 2>(RB, d, wc1, wc1 + 16384, srow, l16, quad, cobase, acc);
        store_tile<0, false>(RA, acc, B1 + lvl * 128, cobase, srow, l16, quad, zb, nullptr);
        __syncthreads();
        conv_core<4, 2>(RA, d, wc2, wc2 + 16384, srow, l16, quad, cobase, acc);
        store_tile<2, false>(RB, acc, B2 + lvl * 128, cobase, srow, l16, quad, zb, nullptr);
        __syncthreads();
    }

    // ---- level 4 conv1 (d=16)
    {
        const short* wc1 = wq + OFF_C1B + 3 * 32768;
        conv_core<4, 2>(RB, 16, wc1, wc1 + 16384, srow, l16, quad, cobase, acc);
        store_tile<0, false>(RA, acc, B1 + 384, cobase, srow, l16, quad, zb, nullptr);
        __syncthreads();
    }
    // ---- final conv2 (d=16): out = elu(elu(conv+b) + D) + x1 ; rows 64..127
    {
        const short* wc2 = wq + OFF_C2B + 3 * 32768;
        conv_core<4, 2>(RA, 16, wc2, wc2 + 16384, srow, l16, quad, cobase, acc);
        if (sq >= 2) {
            #pragma unroll
            for (int mt = 0; mt < 4; ++mt) {
                const int co4 = cobase + mt * 16 + quad * 4;
                const floatx4 bb = *(const floatx4*)(B2 + 384 + co4);
                #pragma unroll
                for (int nt = 0; nt < 2; ++nt) {
                    const int sl = srow + nt * 16 + l16;
                    const int sg = s0g + sl;
                    const short4v res = *(const short4v*)(RB + sl * STRIDE + co4);
                    const short4v k   = x1keep[mt * 2 + nt];
                    #pragma unroll
                    for (int rr = 0; rr < 4; ++rr) {
                        float y = elu_f(acc[mt][nt][rr] + bb[rr]);
                        y = elu_f(y + bs2f(res[rr]));
                        y += bs2f(k[rr]);
                        out[((size_t)(b * 128 + co4 + rr)) * S_LEN + sg] = y;
                    }
                }
            }
        }
    }
}

// ---------------------------------------------------------------------------
// weights fp32 [co][ci][k] -> bf16 tap matrices [co][ci]
// ---------------------------------------------------------------------------
__global__ __launch_bounds__(256)
void prep_w(const float* __restrict__ w1_0, const float* __restrict__ w2_0,
            const float* __restrict__ ds_w, const float* __restrict__ W1,
            const float* __restrict__ W2, short* __restrict__ wq)
{
    int idx = blockIdx.x * 256 + threadIdx.x;
    const int n_c1 = 128 * 64;
    const int n_c2 = 128 * 128;
    if (idx < n_c1) {
        wq[OFF_L0C1_0 + idx] = f2bs(w1_0[idx * 2]);
        wq[OFF_L0C1_1 + idx] = f2bs(w1_0[idx * 2 + 1]);
        return;
    }
    idx -= n_c1;
    if (idx < n_c2) {
        wq[OFF_L0C2_0 + idx] = f2bs(w2_0[idx * 2]);
        wq[OFF_L0C2_1 + idx] = f2bs(w2_0[idx * 2 + 1]);
        return;
    }
    idx -= n_c2;
    if (idx < 4 * n_c2) {
        const int li = idx / n_c2, j = idx - li * n_c2;
        wq[OFF_C1B + li * 32768 + j]         = f2bs(W1[(li * n_c2 + j) * 2]);
        wq[OFF_C1B + li * 32768 + 16384 + j] = f2bs(W1[(li * n_c2 + j) * 2 + 1]);
        return;
    }
    idx -= 4 * n_c2;
    if (idx < 4 * n_c2) {
        const int li = idx / n_c2, j = idx - li * n_c2;
        wq[OFF_C2B + li * 32768 + j]         = f2bs(W2[(li * n_c2 + j) * 2]);
        wq[OFF_C2B + li * 32768 + 16384 + j] = f2bs(W2[(li * n_c2 + j) * 2 + 1]);
        return;
    }
    idx -= 4 * n_c2;
    if (idx < n_c1) wq[OFF_DS + idx] = f2bs(ds_w[idx]);
}

// ---------------------------------------------------------------------------
extern "C" void kernel_launch(void* const* d_in, const int* in_sizes, int n_in,
                              void* d_out, int out_size, void* d_ws, size_t ws_size,
                              hipStream_t stream) {
    const float* x_in = (const float*)d_in[0];
    const float* w1_0 = (const float*)d_in[1];
    const float* b1_0 = (const float*)d_in[2];
    const float* w2_0 = (const float*)d_in[3];
    const float* b2_0 = (const float*)d_in[4];
    const float* ds_w = (const float*)d_in[5];
    const float* ds_b = (const float*)d_in[6];
    const float* W1   = (const float*)d_in[7];
    const float* B1   = (const float*)d_in[8];
    const float* W2   = (const float*)d_in[9];
    const float* B2   = (const float*)d_in[10];
    float* out = (float*)d_out;

    short* wq = (short*)d_ws;   // 624 KB weight bank

    (void)hipFuncSetAttribute((const void*)tcn_fused,
                              hipFuncAttributeMaxDynamicSharedMemorySize, LDS_BYTES);

    prep_w<<<dim3(640), 256, 0, stream>>>(w1_0, w2_0, ds_w, W1, W2, wq);
    tcn_fused<<<dim3(64, 16), dim3(512), LDS_BYTES, stream>>>(
        x_in, wq, b1_0, b2_0, ds_b, B1, B2, out);
}

// Round 10
// 223.083 us; speedup vs baseline: 1.7601x; 1.7601x over previous
//
#include <hip/hip_runtime.h>
#include <hip/hip_bf16.h>
#include <math.h>

// Fully-fused TCN, R9 (resubmit — previous bench was an infra failure):
// window=192 rows (128 outputs/block, grid 32x16 = 512 blocks = exactly 2
// generations at 1 block/CU). Weights are staged in LDS (one tap at a time,
// 34.8 KB region) so MFMA weight fragments come from ds_read_b128 instead of
// per-wave L2 refetch (8x less L2 weight traffic). 2 activation regions
// (192x136 bf16) + weight region = 139.3 KB LDS. Level-0 skip (x1) kept in
// registers. Packed b64 epilogues.

typedef __attribute__((ext_vector_type(8))) short short8;
typedef __attribute__((ext_vector_type(4))) short short4v;
typedef __attribute__((ext_vector_type(4))) float floatx4;

#define S_LEN 4096
#define STRIDE 136                 // 128 ch + 8 pad (bf16 elems)
#define ROWS 192                   // 64 halo + 128 outputs
#define AREG (ROWS * STRIDE)       // 26112 shorts per activation region
#define WREG (128 * STRIDE)        // 17408 shorts weight region
#define LDS_BYTES ((2 * AREG + WREG) * 2)   // 139264 B

// weight bank offsets (bf16-bit shorts)
#define OFF_L0C1_0 0
#define OFF_L0C1_1 8192
#define OFF_L0C2_0 16384
#define OFF_L0C2_1 32768
#define OFF_DS     49152
#define OFF_C1B    57344      // + lvl*32768 ; tap1 at +16384
#define OFF_C2B    188416     // + lvl*32768 ; tap1 at +16384

__device__ __forceinline__ float elu_f(float v) {
    return v > 0.0f ? v : (__expf(v) - 1.0f);
}
__device__ __forceinline__ short f2bs(float v) {
    __hip_bfloat16 h = __float2bfloat16(v);
    return *reinterpret_cast<short*>(&h);
}
__device__ __forceinline__ float bs2f(short s) {
    __hip_bfloat16 h = *reinterpret_cast<__hip_bfloat16*>(&s);
    return __bfloat162float(h);
}
__device__ __forceinline__ short4v pack4(const floatx4 v) {
    __hip_bfloat162 p0 = __float22bfloat162_rn(make_float2(v[0], v[1]));
    __hip_bfloat162 p1 = __float22bfloat162_rn(make_float2(v[2], v[3]));
    short4v r;
    r[0] = ((const short*)&p0)[0]; r[1] = ((const short*)&p0)[1];
    r[2] = ((const short*)&p1)[0]; r[3] = ((const short*)&p1)[1];
    return r;
}

// ---------------------------------------------------------------------------
// Stage one weight tap matrix [128][CIN] (bf16 shorts) into LDS with +8 pad.
// 512 threads, 16B/thread/iter, coalesced global reads, conflict-free writes.
// ---------------------------------------------------------------------------
template<int CIN>
__device__ __forceinline__ void stage_w(short* __restrict__ Lw,
                                        const short* __restrict__ src, int tid)
{
    constexpr int VPR = CIN / 8;          // short8 per row
    #pragma unroll
    for (int v = tid; v < 128 * VPR; v += 512) {
        const int r = v / VPR;
        const int c = (v - r * VPR) * 8;
        *(short8*)(Lw + r * STRIDE + c) = *(const short8*)(src + r * CIN + c);
    }
}

// ---------------------------------------------------------------------------
// One tap's MFMAs: acc[mt][nt] += W[co][ci] * X[r - doff][ci].
// W fragments AND X fragments both from LDS (ds_read_b128 -> MFMA).
// Wave covers 64 co (4 mt) x 48 rows (3 nt).
// ---------------------------------------------------------------------------
template<int KCH>
__device__ __forceinline__ void conv_tap(
    const short* __restrict__ Lin, const short* __restrict__ Lw,
    const int doff, const int srow, const int l16, const int quad,
    const int cobase, floatx4 (&acc)[4][3])
{
    #pragma unroll
    for (int kc = 0; kc < KCH; ++kc) {
        const int col = kc * 32 + quad * 8;
        short8 wf[4];
        #pragma unroll
        for (int mt = 0; mt < 4; ++mt)
            wf[mt] = *(const short8*)(Lw + (cobase + mt * 16 + l16) * STRIDE + col);
        #pragma unroll
        for (int nt = 0; nt < 3; ++nt) {
            int r = srow + nt * 16 + l16 - doff;
            if (r < 0) r = 0;              // clamped rows never feed valid outputs
            const short8 bf = *(const short8*)(Lin + r * STRIDE + col);
            #pragma unroll
            for (int mt = 0; mt < 4; ++mt)
                acc[mt][nt] = __builtin_amdgcn_mfma_f32_16x16x32_bf16(wf[mt], bf, acc[mt][nt], 0, 0, 0);
        }
    }
}

__device__ __forceinline__ void zero_acc(floatx4 (&acc)[4][3]) {
    #pragma unroll
    for (int mt = 0; mt < 4; ++mt)
        #pragma unroll
        for (int nt = 0; nt < 3; ++nt) acc[mt][nt] = {0.f, 0.f, 0.f, 0.f};
}

// ---------------------------------------------------------------------------
// Packed epilogue. Lane holds co = cobase+mt*16+quad*4+rr at row srow+nt*16+l16.
// MODE 0: elu(acc+b) ; MODE 1: acc+b ; MODE 2: elu(elu(acc+b)+dst) (in-place res)
// ---------------------------------------------------------------------------
template<int MODE, bool KEEP>
__device__ __forceinline__ void store_tile(short* __restrict__ dst,
    const floatx4 (&acc)[4][3], const float* __restrict__ bias,
    int cobase, int srow, int l16, int quad, int zero_below, short4v* keep)
{
    #pragma unroll
    for (int mt = 0; mt < 4; ++mt) {
        const int co4 = cobase + mt * 16 + quad * 4;
        const floatx4 bb = *(const floatx4*)(bias + co4);
        #pragma unroll
        for (int nt = 0; nt < 3; ++nt) {
            const int sl = srow + nt * 16 + l16;
            short* p = dst + sl * STRIDE + co4;
            floatx4 y;
            #pragma unroll
            for (int rr = 0; rr < 4; ++rr) {
                float v = acc[mt][nt][rr] + bb[rr];
                if (MODE != 1) v = elu_f(v);
                y[rr] = v;
            }
            if (MODE == 2) {
                const short4v old = *(const short4v*)p;
                #pragma unroll
                for (int rr = 0; rr < 4; ++rr) y[rr] = elu_f(y[rr] + bs2f(old[rr]));
            }
            if (sl < zero_below) y = {0.f, 0.f, 0.f, 0.f};
            const short4v pk = pack4(y);
            *(short4v*)p = pk;
            if (KEEP) keep[mt * 3 + nt] = pk;
        }
    }
}

// ---------------------------------------------------------------------------
__global__ __launch_bounds__(512, 2)
void tcn_fused(const float* __restrict__ x,     // fp32 [16,64,4096] channel-first
               const short* __restrict__ wq,
               const float* __restrict__ b1_0, const float* __restrict__ b2_0,
               const float* __restrict__ ds_b, const float* __restrict__ B1,
               const float* __restrict__ B2, float* __restrict__ out)
{
    extern __shared__ short L[];
    short* RA = L;                 // T buffer (also X staging, cols 0..63)
    short* RB = L + AREG;          // D buffer (residual chain)
    short* LW = L + 2 * AREG;      // weight tap region

    const int tid  = threadIdx.x;
    const int wave = tid >> 6, lane = tid & 63;
    const int l16  = lane & 15, quad = lane >> 4;
    const int coh  = wave & 1,  sq   = wave >> 1;
    const int cobase = coh * 64;
    const int srow   = sq * 48;
    const int s0  = blockIdx.x * 128;
    const int s0g = s0 - 64;
    const int b   = blockIdx.y;
    const int zb  = (s0 == 0) ? 64 : 0;   // zero rows with global s < 0

    // ---- stage X: fp32 channel-first -> bf16 [row][ci] in RA (cols 0..63)
    {
        const float* xp = x + (size_t)b * 64 * S_LEN;
        #pragma unroll
        for (int c8 = 0; c8 < 8; ++c8) {
            const int c = wave * 8 + c8;
            #pragma unroll
            for (int h = 0; h < 3; ++h) {
                const int r = lane + h * 64;
                const int s = s0g + r;
                const float v = (s >= 0) ? xp[c * S_LEN + s] : 0.f;
                RA[r * STRIDE + c] = f2bs(v);
            }
        }
    }

    floatx4 acc[4][3];
    short4v x1keep[12];

    // ---- ds (1x1, CIN=64): reads X(RA), writes RB
    stage_w<64>(LW, wq + OFF_DS, tid);
    __syncthreads();                      // X + weights staged
    zero_acc(acc);
    conv_tap<2>(RA, LW, 0, srow, l16, quad, cobase, acc);
    store_tile<1, false>(RB, acc, ds_b, cobase, srow, l16, quad, zb, nullptr);
    __syncthreads();                      // ds LW reads done

    // ---- conv1_0 (d=1, CIN=64): reads X(RA), writes T over RA
    stage_w<64>(LW, wq + OFF_L0C1_0, tid);
    __syncthreads();
    zero_acc(acc);
    conv_tap<2>(RA, LW, 1, srow, l16, quad, cobase, acc);
    __syncthreads();
    stage_w<64>(LW, wq + OFF_L0C1_1, tid);
    __syncthreads();
    conv_tap<2>(RA, LW, 0, srow, l16, quad, cobase, acc);
    __syncthreads();                      // all X reads done before overwrite
    store_tile<0, false>(RA, acc, b1_0, cobase, srow, l16, quad, zb, nullptr);
    __syncthreads();

    // ---- c2_0 (d=1, CIN=128): reads T(RA), res RB -> RB in place; keep x1
    stage_w<128>(LW, wq + OFF_L0C2_0, tid);
    __syncthreads();
    zero_acc(acc);
    conv_tap<4>(RA, LW, 1, srow, l16, quad, cobase, acc);
    __syncthreads();
    stage_w<128>(LW, wq + OFF_L0C2_1, tid);
    __syncthreads();
    conv_tap<4>(RA, LW, 0, srow, l16, quad, cobase, acc);
    store_tile<2, true>(RB, acc, b2_0, cobase, srow, l16, quad, zb, x1keep);
    __syncthreads();

    // ---- levels 1..3 (d = 2, 4, 8)
    #pragma unroll
    for (int lvl = 0; lvl < 3; ++lvl) {
        const int d = 2 << lvl;
        const short* wc1 = wq + OFF_C1B + lvl * 32768;
        const short* wc2 = wq + OFF_C2B + lvl * 32768;
        // conv1: RB -> RA
        stage_w<128>(LW, wc1, tid);
        __syncthreads();
        zero_acc(acc);
        conv_tap<4>(RB, LW, d, srow, l16, quad, cobase, acc);
        __syncthreads();
        stage_w<128>(LW, wc1 + 16384, tid);
        __syncthreads();
        conv_tap<4>(RB, LW, 0, srow, l16, quad, cobase, acc);
        store_tile<0, false>(RA, acc, B1 + lvl * 128, cobase, srow, l16, quad, zb, nullptr);
        __syncthreads();
        // conv2: RA, res RB -> RB
        stage_w<128>(LW, wc2, tid);
        __syncthreads();
        zero_acc(acc);
        conv_tap<4>(RA, LW, d, srow, l16, quad, cobase, acc);
        __syncthreads();
        stage_w<128>(LW, wc2 + 16384, tid);
        __syncthreads();
        conv_tap<4>(RA, LW, 0, srow, l16, quad, cobase, acc);
        store_tile<2, false>(RB, acc, B2 + lvl * 128, cobase, srow, l16, quad, zb, nullptr);
        __syncthreads();
    }

    // ---- level 4 conv1 (d=16): RB -> RA
    {
        const short* wc1 = wq + OFF_C1B + 3 * 32768;
        stage_w<128>(LW, wc1, tid);
        __syncthreads();
        zero_acc(acc);
        conv_tap<4>(RB, LW, 16, srow, l16, quad, cobase, acc);
        __syncthreads();
        stage_w<128>(LW, wc1 + 16384, tid);
        __syncthreads();
        conv_tap<4>(RB, LW, 0, srow, l16, quad, cobase, acc);
        store_tile<0, false>(RA, acc, B1 + 384, cobase, srow, l16, quad, zb, nullptr);
        __syncthreads();
    }
    // ---- final conv2 (d=16): out = elu(elu(conv+b) + RB) + x1 ; rows 64..191
    {
        const short* wc2 = wq + OFF_C2B + 3 * 32768;
        stage_w<128>(LW, wc2, tid);
        __syncthreads();
        zero_acc(acc);
        conv_tap<4>(RA, LW, 16, srow, l16, quad, cobase, acc);
        __syncthreads();
        stage_w<128>(LW, wc2 + 16384, tid);
        __syncthreads();
        conv_tap<4>(RA, LW, 0, srow, l16, quad, cobase, acc);

        #pragma unroll
        for (int mt = 0; mt < 4; ++mt) {
            const int co4 = cobase + mt * 16 + quad * 4;
            const floatx4 bb = *(const floatx4*)(B2 + 384 + co4);
            #pragma unroll
            for (int nt = 0; nt < 3; ++nt) {
                if (srow + nt * 16 < 64) continue;     // halo rows: no output
                const int sl = srow + nt * 16 + l16;
                const int sg = s0g + sl;
                const short4v res = *(const short4v*)(RB + sl * STRIDE + co4);
                const short4v k   = x1keep[mt * 3 + nt];
                #pragma unroll
                for (int rr = 0; rr < 4; ++rr) {
                    float y = elu_f(acc[mt][nt][rr] + bb[rr]);
                    y = elu_f(y + bs2f(res[rr]));
                    y += bs2f(k[rr]);
                    out[((size_t)(b * 128 + co4 + rr)) * S_LEN + sg] = y;
                }
            }
        }
    }
}

// ---------------------------------------------------------------------------
// weights fp32 [co][ci][k] -> bf16 tap matrices [co][ci]
// ---------------------------------------------------------------------------
__global__ __launch_bounds__(256)
void prep_w(const float* __restrict__ w1_0, const float* __restrict__ w2_0,
            const float* __restrict__ ds_w, const float* __restrict__ W1,
            const float* __restrict__ W2, short* __restrict__ wq)
{
    int idx = blockIdx.x * 256 + threadIdx.x;
    const int n_c1 = 128 * 64;
    const int n_c2 = 128 * 128;
    if (idx < n_c1) {
        wq[OFF_L0C1_0 + idx] = f2bs(w1_0[idx * 2]);
        wq[OFF_L0C1_1 + idx] = f2bs(w1_0[idx * 2 + 1]);
        return;
    }
    idx -= n_c1;
    if (idx < n_c2) {
        wq[OFF_L0C2_0 + idx] = f2bs(w2_0[idx * 2]);
        wq[OFF_L0C2_1 + idx] = f2bs(w2_0[idx * 2 + 1]);
        return;
    }
    idx -= n_c2;
    if (idx < 4 * n_c2) {
        const int li = idx / n_c2, j = idx - li * n_c2;
        wq[OFF_C1B + li * 32768 + j]         = f2bs(W1[(li * n_c2 + j) * 2]);
        wq[OFF_C1B + li * 32768 + 16384 + j] = f2bs(W1[(li * n_c2 + j) * 2 + 1]);
        return;
    }
    idx -= 4 * n_c2;
    if (idx < 4 * n_c2) {
        const int li = idx / n_c2, j = idx - li * n_c2;
        wq[OFF_C2B + li * 32768 + j]         = f2bs(W2[(li * n_c2 + j) * 2]);
        wq[OFF_C2B + li * 32768 + 16384 + j] = f2bs(W2[(li * n_c2 + j) * 2 + 1]);
        return;
    }
    idx -= 4 * n_c2;
    if (idx < n_c1) wq[OFF_DS + idx] = f2bs(ds_w[idx]);
}

// ---------------------------------------------------------------------------
extern "C" void kernel_launch(void* const* d_in, const int* in_sizes, int n_in,
                              void* d_out, int out_size, void* d_ws, size_t ws_size,
                              hipStream_t stream) {
    const float* x_in = (const float*)d_in[0];
    const float* w1_0 = (const float*)d_in[1];
    const float* b1_0 = (const float*)d_in[2];
    const float* w2_0 = (const float*)d_in[3];
    const float* b2_0 = (const float*)d_in[4];
    const float* ds_w = (const float*)d_in[5];
    const float* ds_b = (const float*)d_in[6];
    const float* W1   = (const float*)d_in[7];
    const float* B1   = (const float*)d_in[8];
    const float* W2   = (const float*)d_in[9];
    const float* B2   = (const float*)d_in[10];
    float* out = (float*)d_out;

    short* wq = (short*)d_ws;   // 624 KB weight bank

    (void)hipFuncSetAttribute((const void*)tcn_fused,
                              hipFuncAttributeMaxDynamicSharedMemorySize, LDS_BYTES);

    prep_w<<<dim3(640), 256, 0, stream>>>(w1_0, w2_0, ds_w, W1, W2, wq);
    tcn_fused<<<dim3(32, 16), dim3(512), LDS_BYTES, stream>>>(
        x_in, wq, b1_0, b2_0, ds_b, B1, B2, out);
}